// Round 10
// baseline (173.729 us; speedup 1.0000x reference)
//
#include <hip/hip_runtime.h>
#include <hip/hip_bf16.h>
#include <cstdint>

#define NN 50000
#define NE 800000
#define HD 128
#define OD 64
#define NG 64
#define NBUCK 196          // buckets of 256 dst nodes
#define SCHUNK 4096        // edges per scatter block
#define SBLOCKS 196        // ceil(800000/4096)
#define CSR_CAP 5120       // per-bucket capacity (mean 4082, +16 sigma)
#define GEMM_BLOCKS 782    // ceil(50000/64)

typedef unsigned int uint32;
typedef unsigned short u16;
typedef _Float16 f16;
typedef _Float16 f16x8 __attribute__((ext_vector_type(8)));
typedef float f32x4 __attribute__((ext_vector_type(4)));

static __device__ __forceinline__ u16 f2h(float f) {
    f16 h = (f16)f;                       // v_cvt_f16_f32, RTNE
    return __builtin_bit_cast(u16, h);
}
static __device__ __forceinline__ float h2f(u16 u) {
    return (float)__builtin_bit_cast(f16, u);
}
static __device__ __forceinline__ uint32 pkh2(float x, float y) {
    return (uint32)f2h(x) | ((uint32)f2h(y) << 16);
}
static __device__ __forceinline__ void add8(float* a, uint4 m) {
    a[0] += h2f((u16)(m.x & 0xffffu)); a[1] += h2f((u16)(m.x >> 16));
    a[2] += h2f((u16)(m.y & 0xffffu)); a[3] += h2f((u16)(m.y >> 16));
    a[4] += h2f((u16)(m.z & 0xffffu)); a[5] += h2f((u16)(m.z >> 16));
    a[6] += h2f((u16)(m.w & 0xffffu)); a[7] += h2f((u16)(m.w >> 16));
}
// epilogue LDS transpose swizzle (involution, 16B-granular)
static __device__ __forceinline__ int swz(int row) {
    return ((row & 7) << 4) | ((row & 8) << 3);
}

// shared gather: node v, 16 lanes/edge (slot=lane>>4, colg=lane&15), 4-deep unroll.
// On return ALL 64 lanes hold the full fp32 sums for chunk colg (8 cols).
static __device__ __forceinline__ void agg_node(const uint4* __restrict__ hp16,
                                                const uint32* __restrict__ packed,
                                                const u16* __restrict__ csr,
                                                int v, int slot, int colg, float* acc) {
#pragma unroll
    for (int j = 0; j < 8; ++j) acc[j] = 0.f;
    if (slot == 0) {                       // self loop counted once
        uint4 m = hp16[(size_t)v * 16 + colg];
        add8(acc, m);
    }
    uint32 pk = packed[v];
    const int e0 = (int)(pk & 0xFFFFFu);
    const int end = e0 + (int)(pk >> 20);
    int idx = e0 + slot;
    for (; idx + 12 < end; idx += 16) {
        int s0 = csr[idx], s1 = csr[idx + 4], s2 = csr[idx + 8], s3 = csr[idx + 12];
        uint4 m0 = hp16[(size_t)s0 * 16 + colg];
        uint4 m1 = hp16[(size_t)s1 * 16 + colg];
        uint4 m2 = hp16[(size_t)s2 * 16 + colg];
        uint4 m3 = hp16[(size_t)s3 * 16 + colg];
        add8(acc, m0); add8(acc, m1); add8(acc, m2); add8(acc, m3);
    }
    for (; idx < end; idx += 4) {
        int s = csr[idx];
        uint4 m = hp16[(size_t)s * 16 + colg];
        add8(acc, m);
    }
#pragma unroll
    for (int j = 0; j < 8; ++j) {
        acc[j] += __shfl_xor(acc[j], 16, 64);
        acc[j] += __shfl_xor(acc[j], 32, 64);
    }
}

// ---------- prep: pack W1,W2 to fp16 frag order; zero bucket_fill + pooled ----------
// sigma: k = ks*32 + (lane>>4)*8 + j ; n = ct*16 + (lane&15); A,B share sigma.

__global__ __launch_bounds__(256) void k_prep(const float* __restrict__ W1,
                                              const float* __restrict__ W2,
                                              u16* __restrict__ pw1,
                                              u16* __restrict__ pw2,
                                              int* __restrict__ bucket_fill,
                                              float* __restrict__ pooled) {
    int b = blockIdx.x, t = threadIdx.x;
    if (b == 16) {
        if (t < NBUCK) bucket_fill[t] = 0;
        float4 z = make_float4(0.f, 0.f, 0.f, 0.f);
#pragma unroll
        for (int i = 0; i < 8; ++i) ((float4*)pooled)[i * 256 + t] = z;
        return;
    }
    const float* W = (b < 8) ? W1 : W2;
    u16* pw = (b < 8) ? pw1 : pw2;
    int tau = (b & 7) * 256 + t;                // 0..2047
    int lane = tau & 63, ct = (tau >> 6) & 7, ks = (tau >> 9) & 3;
    int g = lane >> 4, n = ct * 16 + (lane & 15);
    uint32 pk[4];
#pragma unroll
    for (int jp = 0; jp < 4; ++jp) {
        int k = ks * 32 + g * 8 + jp * 2;
        uint32 lo = f2h(W[k * 128 + n]);
        uint32 hi = f2h(W[(k + 1) * 128 + n]);
        pk[jp] = lo | (hi << 16);
    }
    ((uint4*)pw)[(size_t)((ks * 8 + ct) * 64 + lane)] = make_uint4(pk[0], pk[1], pk[2], pk[3]);
}

// ---------- single-pass bucketed scatter into fixed-capacity strided buckets ----------

__global__ __launch_bounds__(256) void k_scatter(const int* __restrict__ src,
                                                 const int* __restrict__ dst,
                                                 int* __restrict__ bucket_fill,
                                                 uint32* __restrict__ grec) {
    __shared__ uint32 rin[SCHUNK];
    __shared__ uint32 rout[SCHUNK];
    __shared__ int lh[256], ls[256], lf[256], lgb[256];
    int t = threadIdx.x;
    lh[t] = 0; lf[t] = 0;
    __syncthreads();
    int e0 = blockIdx.x * SCHUNK;
    int ne = min(SCHUNK, NE - e0);
    for (int k = 0; k < 16; ++k) {
        int i = k * 256 + t;
        if (i < ne) {
            uint32 rec = ((uint32)dst[e0 + i] << 16) | (uint32)src[e0 + i];
            rin[i] = rec;
            atomicAdd(&lh[rec >> 24], 1);
        }
    }
    __syncthreads();
    int v = lh[t];
    ls[t] = v; __syncthreads();
    for (int off = 1; off < 256; off <<= 1) {
        int u = (t >= off) ? ls[t - off] : 0;
        __syncthreads();
        ls[t] += u;
        __syncthreads();
    }
    int excl = ls[t] - v;
    __syncthreads();
    ls[t] = excl;
    if (t < NBUCK && v > 0) lgb[t] = atomicAdd(&bucket_fill[t], v);
    __syncthreads();
    for (int k = 0; k < 16; ++k) {
        int i = k * 256 + t;
        if (i < ne) {
            uint32 rec = rin[i];
            int b = rec >> 24;
            int p = ls[b] + atomicAdd(&lf[b], 1);
            rout[p] = rec;
        }
    }
    __syncthreads();
    for (int k = 0; k < 16; ++k) {
        int i = k * 256 + t;
        if (i < ne) {
            uint32 rec = rout[i];
            int b = rec >> 24;
            int pos = lgb[b] + (i - ls[b]);
            if (pos < CSR_CAP) grec[(size_t)b * CSR_CAP + pos] = rec;
        }
    }
}

// ---------- per-bucket counting sort -> u16 CSR + packed (rs|deg<<20) + dinv ----------

__global__ __launch_bounds__(256) void k_csr(const uint32* __restrict__ grec,
                                             const int* __restrict__ bucket_fill,
                                             uint32* __restrict__ packed,
                                             float* __restrict__ dinv,
                                             u16* __restrict__ csr) {
    __shared__ uint32 rin[CSR_CAP];
    __shared__ u16 sorted[CSR_CAP];
    __shared__ int cnt_l[256], off_l[256], fill_l[256];
    const int b = blockIdx.x, t = threadIdx.x;
    const int s0 = b * CSR_CAP;
    const int n = min(bucket_fill[b], CSR_CAP);
    cnt_l[t] = 0; fill_l[t] = 0;
    __syncthreads();
    for (int i = t; i < n; i += 256) {
        uint32 r = grec[s0 + i];
        rin[i] = r;
        atomicAdd(&cnt_l[(r >> 16) & 255], 1);
    }
    __syncthreads();
    int v = cnt_l[t];
    off_l[t] = v; __syncthreads();
    for (int off = 1; off < 256; off <<= 1) {
        int u = (t >= off) ? off_l[t - off] : 0;
        __syncthreads();
        off_l[t] += u;
        __syncthreads();
    }
    int excl = off_l[t] - v;
    __syncthreads();
    off_l[t] = excl;
    int vtx = (b << 8) + t;
    if (vtx < NN) {
        packed[vtx] = (uint32)(s0 + excl) | ((uint32)v << 20);
        dinv[vtx] = rsqrtf((float)(v + 1));   // +1 self-loop
    }
    __syncthreads();
    for (int i = t; i < n; i += 256) {
        uint32 r = rin[i];
        int d = (r >> 16) & 255;
        int p = off_l[d] + atomicAdd(&fill_l[d], 1);
        sorted[p] = (u16)(r & 0xffffu);
    }
    __syncthreads();
    for (int i = t; i < n; i += 256) csr[s0 + i] = sorted[i];
}

// ---------- MFMA GEMM (fp32 input): hp = f16((X @ W) * dinv) ----------

__global__ __launch_bounds__(256, 2) void k_gemm_f32(const float* __restrict__ X,
                                                     const u16* __restrict__ pw,
                                                     const float* __restrict__ dinv,
                                                     u16* __restrict__ hp, int nrows) {
    __shared__ u16 xp[8192];    // 16 KB A-frags, reused for epilogue
    const int t = threadIdx.x, lane = t & 63, wv = t >> 6;
    const int r0 = blockIdx.x * 64;
    const float4* X4 = (const float4*)X;
#pragma unroll
    for (int it = 0; it < 8; ++it) {
        int idx = it * 256 + t;          // 64 rows x 32 float4-cols
        int rloc = idx >> 5, kq = idx & 31;
        int rr = r0 + rloc;
        float4 xv = (rr < nrows) ? X4[(size_t)rr * 32 + kq]
                                 : make_float4(0.f, 0.f, 0.f, 0.f);
        int ks = kq >> 3, g = (kq >> 1) & 3, half = kq & 1;
        int wvd = rloc >> 4, ln = (rloc & 15) + 16 * g;
        ushort4 p;
        p.x = f2h(xv.x); p.y = f2h(xv.y); p.z = f2h(xv.z); p.w = f2h(xv.w);
        *(ushort4*)&xp[(((ks * 4 + wvd) * 64 + ln) << 3) + half * 4] = p;
    }
    __syncthreads();
    f32x4 acc[8];
#pragma unroll
    for (int c = 0; c < 8; ++c) acc[c] = (f32x4){0.f, 0.f, 0.f, 0.f};
#pragma unroll
    for (int ks = 0; ks < 4; ++ks) {
        f16x8 a = *reinterpret_cast<f16x8*>(&xp[((ks * 4 + wv) * 64 + lane) << 3]);
#pragma unroll
        for (int ct = 0; ct < 8; ++ct) {
            f16x8 b = *reinterpret_cast<const f16x8*>(pw + ((size_t)((ks * 8 + ct) * 64 + lane) << 3));
            acc[ct] = __builtin_amdgcn_mfma_f32_16x16x32_f16(a, b, acc[ct], 0, 0, 0);
        }
    }
    float dv[4];
#pragma unroll
    for (int r = 0; r < 4; ++r) {
        int m = r0 + wv * 16 + 4 * (lane >> 4) + r;
        dv[r] = (m < nrows) ? dinv[m] : 0.f;
    }
    __syncthreads();
#pragma unroll
    for (int ct = 0; ct < 8; ++ct)
#pragma unroll
        for (int r = 0; r < 4; ++r) {
            int row_local = wv * 16 + 4 * (lane >> 4) + r;
            int colb = ct * 32 + (lane & 15) * 2;
            int byte = row_local * 256 + (colb ^ swz(row_local));
            xp[byte >> 1] = f2h(acc[ct][r] * dv[r]);
        }
    __syncthreads();
#pragma unroll
    for (int p = 0; p < 4; ++p) {
        int row_local = t >> 2;
        int chunk = (t & 3) + 4 * p;
        int byte = row_local * 256 + ((chunk * 16) ^ swz(row_local));
        uint4 val = *reinterpret_cast<uint4*>(&xp[byte >> 1]);
        int rr = r0 + row_local;
        if (rr < nrows) ((uint4*)hp)[(size_t)rr * 16 + chunk] = val;
    }
}

// ---------- FUSED agg1 + gemm2: hp2 = f16( (relu(agg(hp)+b1) @ W2) * dinv ) ----------
// Phase A: each wave aggregates 16 nodes, writes rows straight into A-frag LDS.
// Phase B: identical MFMA+epilogue as k_gemm_f32.

__global__ __launch_bounds__(256, 2) void k_aggemm(const uint32* __restrict__ hp,
                                                   const uint32* __restrict__ packed,
                                                   const u16* __restrict__ csr,
                                                   const float* __restrict__ dinv,
                                                   const float* __restrict__ bias,
                                                   const u16* __restrict__ pw,
                                                   u16* __restrict__ hp2, int nrows) {
    __shared__ u16 xp[8192];
    const int t = threadIdx.x, lane = t & 63, wv = t >> 6;
    const int r0 = blockIdx.x * 64;
    const int slot = lane >> 4, colg = lane & 15;
    const uint4* hp16 = (const uint4*)hp;
    const float4 ba = ((const float4*)bias)[colg * 2];
    const float4 bb = ((const float4*)bias)[colg * 2 + 1];

    // Phase A: aggregate + bias + relu -> fp16 A-frags in LDS
    for (int i = 0; i < 16; ++i) {
        int rloc = wv * 16 + i;
        int v = r0 + rloc;
        float acc[8];
        if (v < NN) {
            agg_node(hp16, packed, csr, v, slot, colg, acc);
        } else {
#pragma unroll
            for (int j = 0; j < 8; ++j) acc[j] = 0.f;
        }
        if (slot == 0) {
            float dvv = (v < NN) ? dinv[v] : 0.f;
            uint4 o4;
            o4.x = pkh2(fmaxf(acc[0] * dvv + ba.x, 0.f), fmaxf(acc[1] * dvv + ba.y, 0.f));
            o4.y = pkh2(fmaxf(acc[2] * dvv + ba.z, 0.f), fmaxf(acc[3] * dvv + ba.w, 0.f));
            o4.z = pkh2(fmaxf(acc[4] * dvv + bb.x, 0.f), fmaxf(acc[5] * dvv + bb.y, 0.f));
            o4.w = pkh2(fmaxf(acc[6] * dvv + bb.z, 0.f), fmaxf(acc[7] * dvv + bb.w, 0.f));
            if (v >= NN) o4 = make_uint4(0u, 0u, 0u, 0u);
            int ks = colg >> 2, g = colg & 3, ln = (rloc & 15) + 16 * g;
            *(uint4*)&xp[((ks * 4 + wv) * 64 + ln) << 3] = o4;   // wvd = rloc>>4 = wv
        }
    }
    __syncthreads();

    // Phase B: MFMA + epilogue
    f32x4 acc[8];
#pragma unroll
    for (int c = 0; c < 8; ++c) acc[c] = (f32x4){0.f, 0.f, 0.f, 0.f};
#pragma unroll
    for (int ks = 0; ks < 4; ++ks) {
        f16x8 a = *reinterpret_cast<f16x8*>(&xp[((ks * 4 + wv) * 64 + lane) << 3]);
#pragma unroll
        for (int ct = 0; ct < 8; ++ct) {
            f16x8 b = *reinterpret_cast<const f16x8*>(pw + ((size_t)((ks * 8 + ct) * 64 + lane) << 3));
            acc[ct] = __builtin_amdgcn_mfma_f32_16x16x32_f16(a, b, acc[ct], 0, 0, 0);
        }
    }
    float dv[4];
#pragma unroll
    for (int r = 0; r < 4; ++r) {
        int m = r0 + wv * 16 + 4 * (lane >> 4) + r;
        dv[r] = (m < nrows) ? dinv[m] : 0.f;
    }
    __syncthreads();
#pragma unroll
    for (int ct = 0; ct < 8; ++ct)
#pragma unroll
        for (int r = 0; r < 4; ++r) {
            int row_local = wv * 16 + 4 * (lane >> 4) + r;
            int colb = ct * 32 + (lane & 15) * 2;
            int byte = row_local * 256 + (colb ^ swz(row_local));
            xp[byte >> 1] = f2h(acc[ct][r] * dv[r]);
        }
    __syncthreads();
#pragma unroll
    for (int p = 0; p < 4; ++p) {
        int row_local = t >> 2;
        int chunk = (t & 3) + 4 * p;
        int byte = row_local * 256 + ((chunk * 16) ^ swz(row_local));
        uint4 val = *reinterpret_cast<uint4*>(&xp[byte >> 1]);
        int rr = r0 + row_local;
        if (rr < nrows) ((uint4*)hp2)[(size_t)rr * 16 + chunk] = val;
    }
}

// ---------- FUSED agg2 + pool: pooled[g] += relu(dinv*(agg(hp2))+b2) ----------
// Never materializes layer-2 output; batch sorted -> monotone graph id per wave.

__global__ __launch_bounds__(256) void k_aggpool(const uint32* __restrict__ hp,
                                                 const uint32* __restrict__ packed,
                                                 const u16* __restrict__ csr,
                                                 const float* __restrict__ dinv,
                                                 const float* __restrict__ bias,
                                                 const int* __restrict__ batch,
                                                 float* __restrict__ pooled) {
    const int t = threadIdx.x, lane = t & 63, wv = t >> 6;
    const int r0 = blockIdx.x * 64;
    const int slot = lane >> 4, colg = lane & 15;
    const uint4* hp16 = (const uint4*)hp;
    const float4 ba = ((const float4*)bias)[colg * 2];
    const float4 bb = ((const float4*)bias)[colg * 2 + 1];

    float pl[8];
#pragma unroll
    for (int j = 0; j < 8; ++j) pl[j] = 0.f;
    int curg = -1;

    for (int i = 0; i < 16; ++i) {
        int v = r0 + wv * 16 + i;
        if (v >= NN) break;
        int g = batch[v];
        float acc[8];
        agg_node(hp16, packed, csr, v, slot, colg, acc);
        float dvv = dinv[v];
        float o[8];
        o[0] = fmaxf(acc[0] * dvv + ba.x, 0.f); o[1] = fmaxf(acc[1] * dvv + ba.y, 0.f);
        o[2] = fmaxf(acc[2] * dvv + ba.z, 0.f); o[3] = fmaxf(acc[3] * dvv + ba.w, 0.f);
        o[4] = fmaxf(acc[4] * dvv + bb.x, 0.f); o[5] = fmaxf(acc[5] * dvv + bb.y, 0.f);
        o[6] = fmaxf(acc[6] * dvv + bb.z, 0.f); o[7] = fmaxf(acc[7] * dvv + bb.w, 0.f);
        if (g != curg) {
            if (curg >= 0 && slot == 0) {
#pragma unroll
                for (int j = 0; j < 8; ++j)
                    atomicAdd(&pooled[curg * 128 + colg * 8 + j], pl[j]);
            }
#pragma unroll
            for (int j = 0; j < 8; ++j) pl[j] = 0.f;
            curg = g;
        }
#pragma unroll
        for (int j = 0; j < 8; ++j) pl[j] += o[j];
    }
    if (curg >= 0 && slot == 0) {
#pragma unroll
        for (int j = 0; j < 8; ++j)
            atomicAdd(&pooled[curg * 128 + colg * 8 + j], pl[j]);
    }
}

// ---------- mean + linear head ----------

__global__ __launch_bounds__(256) void k_head(const float* __restrict__ pooled,
                                              const int* __restrict__ batch,
                                              const float* __restrict__ Wl,
                                              const float* __restrict__ bl_,
                                              float* __restrict__ out) {
    int g = blockIdx.x, t = threadIdx.x;
    __shared__ int se[2];
    __shared__ float pm[128];
    __shared__ float part[256];
    if (t < 2) {
        int target = g + t;
        int lo = 0, hi = NN;
        while (lo < hi) {
            int mid = (lo + hi) >> 1;
            if (batch[mid] < target) lo = mid + 1; else hi = mid;
        }
        se[t] = lo;
    }
    __syncthreads();
    int cntg = se[1] - se[0];
    float inv = 1.f / (float)(cntg > 0 ? cntg : 1);
    if (t < 128) pm[t] = pooled[g * 128 + t] * inv;
    __syncthreads();
    int col = t & 63, kh = t >> 6;
    float o = 0.f;
    for (int k = kh * 32; k < kh * 32 + 32; ++k) o += pm[k] * Wl[k * OD + col];
    part[t] = o; __syncthreads();
    if (t < OD)
        out[g * OD + t] = part[t] + part[t + 64] + part[t + 128] + part[t + 192] + bl_[t];
}

// ---------- launcher ----------

extern "C" void kernel_launch(void* const* d_in, const int* in_sizes, int n_in,
                              void* d_out, int out_size, void* d_ws, size_t ws_size,
                              hipStream_t stream) {
    const float* x   = (const float*)d_in[0];
    const int*   ei  = (const int*)d_in[1];
    const int*   bat = (const int*)d_in[2];
    const float* W1  = (const float*)d_in[3];
    const float* b1  = (const float*)d_in[4];
    const float* W2  = (const float*)d_in[5];
    const float* b2  = (const float*)d_in[6];
    const float* Wl  = (const float*)d_in[7];
    const float* bl  = (const float*)d_in[8];
    float* out = (float*)d_out;
    const int* src = ei;
    const int* dst = ei + NE;

    char* w = (char*)d_ws;
    size_t off = 0;
    auto alloc = [&](size_t bytes) -> char* {
        char* p = w + off;
        off = (off + bytes + 255) & ~(size_t)255;
        return p;
    };
    float*  dinv        = (float*)alloc(NN * 4);
    uint32* packed      = (uint32*)alloc(NN * 4);
    int*    bucket_fill = (int*)alloc(NBUCK * 4);
    float*  pooled      = (float*)alloc(NG * HD * 4);
    u16*    pw1         = (u16*)alloc(2048 * 16);
    u16*    pw2         = (u16*)alloc(2048 * 16);
    uint32* grec        = (uint32*)alloc((size_t)NBUCK * CSR_CAP * 4);
    u16*    csr         = (u16*)alloc((size_t)NBUCK * CSR_CAP * 2);
    u16*    hp          = (u16*)alloc((size_t)NN * HD * 2);   // f16 h' (layer 1)
    u16*    hp2         = (u16*)alloc((size_t)NN * HD * 2);   // f16 h' (layer 2)

    k_prep<<<17, 256, 0, stream>>>(W1, W2, pw1, pw2, bucket_fill, pooled);
    k_scatter<<<SBLOCKS, 256, 0, stream>>>(src, dst, bucket_fill, grec);
    k_csr<<<NBUCK, 256, 0, stream>>>(grec, bucket_fill, packed, dinv, csr);

    k_gemm_f32<<<GEMM_BLOCKS, 256, 0, stream>>>(x, pw1, dinv, hp, NN);
    k_aggemm<<<GEMM_BLOCKS, 256, 0, stream>>>((const uint32*)hp, packed, csr, dinv, b1, pw2, hp2, NN);
    k_aggpool<<<GEMM_BLOCKS, 256, 0, stream>>>((const uint32*)hp2, packed, csr, dinv, b2, bat, pooled);
    k_head<<<NG, 256, 0, stream>>>(pooled, bat, Wl, bl, out);
}